// Round 2
// baseline (10236.079 us; speedup 1.0000x reference)
//
#include <hip/hip_runtime.h>

// Problem constants (fixed by reference setup)
#define DIM    256
#define HEADS  8
#define DH     64
#define DPG    32
#define KNB    32
#define INNER  512
#define EPS    1e-5f

// ws layout (float offsets) — only BN stats now; weights are fp32 in d_in
#define WS_SUM  0
#define WS_SSQ  256
#define WS_SC   512
#define WS_SH   768

__global__ __launch_bounds__(256) void bn_stats_k(const float* __restrict__ x,
                                                  float* __restrict__ ws, int rows_per_block) {
    int c = threadIdx.x;                       // channel 0..255
    long long r0 = (long long)blockIdx.x * rows_per_block;
    float s = 0.f, s2 = 0.f;
    const float* p = x + r0 * DIM + c;
    for (int r = 0; r < rows_per_block; ++r) {
        float v = p[(long long)r * DIM];
        s += v; s2 += v * v;
    }
    atomicAdd(&ws[WS_SUM + c], s);
    atomicAdd(&ws[WS_SSQ + c], s2);
}

__global__ __launch_bounds__(256) void bn_finalize_k(const float* __restrict__ g,
                                                     const float* __restrict__ b,
                                                     float* __restrict__ ws, float inv_n) {
    int c = threadIdx.x;
    float mean = ws[WS_SUM + c] * inv_n;
    float var  = ws[WS_SSQ + c] * inv_n - mean * mean;   // biased var (torch BN)
    float sc   = g[c] * rsqrtf(var + EPS);
    ws[WS_SC + c] = sc;
    ws[WS_SH + c] = b[c] - mean * sc;
}

// One block (256 thr = 4 waves) per point; loop over 8 heads, accumulate the
// output Linear into 32 registers/thread (thread owns row r=t>>3, cols (t&7)*32..+31).
__global__ __launch_bounds__(256) void attn_k(const float* __restrict__ x,
                                              const float* __restrict__ ws,
                                              const float* __restrict__ Wq,
                                              const float* __restrict__ Wk,
                                              const float* __restrict__ Wv,
                                              const float* __restrict__ Wout,
                                              const float* __restrict__ bout,
                                              float* __restrict__ out) {
    __shared__ float xs[KNB][DPG + 1];   // padded: break power-of-2 bank strides
    __shared__ float qs[KNB][DH + 1];
    __shared__ float ks[KNB][DH + 1];
    __shared__ float vs[KNB][DH + 1];
    __shared__ float as[KNB][KNB + 1];
    __shared__ float os[KNB][DH + 1];

    const int t   = threadIdx.x;
    const int bp  = blockIdx.x;
    const int r   = t >> 3;          // 0..31 (neighbor row)
    const int oct = t & 7;
    const int cb  = oct * 32;        // output col base

    float acc[32];
    #pragma unroll
    for (int j = 0; j < 32; ++j) acc[j] = 0.f;

    for (int h = 0; h < HEADS; ++h) {
        __syncthreads();   // protect LDS reuse across head iterations
        // ---- 1. load + BN x slice [32 rows x 32 ch of this head's group]
        {
            int c4 = oct * 4;
            const float* xp = x + ((long long)bp * KNB + r) * DIM + h * DPG + c4;
            float4 u = *reinterpret_cast<const float4*>(xp);
            #pragma unroll
            for (int j = 0; j < 4; ++j) {
                int gc = h * DPG + c4 + j;
                xs[r][c4 + j] = (&u.x)[j] * ws[WS_SC + gc] + ws[WS_SH + gc];
            }
        }
        __syncthreads();
        // ---- 2. q/k/v projections: thread computes 8 outputs each (K=32 dots)
        {
            int o0 = oct * 8;
            #pragma unroll
            for (int oo = 0; oo < 8; ++oo) {
                int o = o0 + oo;
                const float* wqp = Wq + (h * DH + o) * DPG;
                const float* wkp = Wk + (h * DH + o) * DPG;
                const float* wvp = Wv + (h * DH + o) * DPG;
                float sq = 0.f, sk = 0.f, sv = 0.f;
                #pragma unroll
                for (int c = 0; c < DPG; ++c) {
                    float xv = xs[r][c];
                    sq += xv * wqp[c];
                    sk += xv * wkp[c];
                    sv += xv * wvp[c];
                }
                qs[r][o] = sq; ks[r][o] = sk; vs[r][o] = sv;
            }
        }
        __syncthreads();
        // ---- 3. dots (row r, cols j0..j0+3) + softmax over the 8-lane octet
        {
            int j0 = oct * 4;
            float d[4] = {0.f, 0.f, 0.f, 0.f};
            for (int dd = 0; dd < DH; ++dd) {
                float qv = qs[r][dd];
                #pragma unroll
                for (int j = 0; j < 4; ++j) d[j] += qv * ks[j0 + j][dd];
            }
            #pragma unroll
            for (int j = 0; j < 4; ++j) d[j] *= 0.125f;   // dim_head^-0.5
            float m = fmaxf(fmaxf(d[0], d[1]), fmaxf(d[2], d[3]));
            m = fmaxf(m, __shfl_xor(m, 1, 8));
            m = fmaxf(m, __shfl_xor(m, 2, 8));
            m = fmaxf(m, __shfl_xor(m, 4, 8));
            float e[4], s = 0.f;
            #pragma unroll
            for (int j = 0; j < 4; ++j) { e[j] = __expf(d[j] - m); s += e[j]; }
            s += __shfl_xor(s, 1, 8);
            s += __shfl_xor(s, 2, 8);
            s += __shfl_xor(s, 4, 8);
            float inv = 1.f / s;
            #pragma unroll
            for (int j = 0; j < 4; ++j) as[r][j0 + j] = e[j] * inv;
        }
        __syncthreads();
        // ---- 4. outh = attn @ v : thread does row r, 8 out-cols
        {
            int o0 = oct * 8;
            float o_[8] = {0.f,0.f,0.f,0.f,0.f,0.f,0.f,0.f};
            for (int j = 0; j < KNB; ++j) {
                float a = as[r][j];
                #pragma unroll
                for (int oo = 0; oo < 8; ++oo) o_[oo] += a * vs[j][o0 + oo];
            }
            #pragma unroll
            for (int oo = 0; oo < 8; ++oo) os[r][o0 + oo] = o_[oo];
        }
        __syncthreads();
        // ---- 5. acc += outh @ Wout[h*64 .. h*64+63, :]
        {
            const float* wbase = Wout + (h * DH) * DIM + cb;
            for (int o = 0; o < DH; ++o) {
                float a = os[r][o];
                const float4* wrow = reinterpret_cast<const float4*>(wbase + o * DIM);
                #pragma unroll
                for (int jv = 0; jv < 8; ++jv) {
                    float4 w = wrow[jv];
                    acc[jv * 4 + 0] += a * w.x;
                    acc[jv * 4 + 1] += a * w.y;
                    acc[jv * 4 + 2] += a * w.z;
                    acc[jv * 4 + 3] += a * w.w;
                }
            }
        }
    }
    // ---- epilogue: + bout, store fp32
    {
        float* op = out + ((long long)bp * KNB + r) * DIM + cb;
        const float* bb = bout + cb;
        #pragma unroll
        for (int jv = 0; jv < 8; ++jv) {
            float4 u;
            #pragma unroll
            for (int j = 0; j < 4; ++j)
                (&u.x)[j] = acc[jv * 4 + j] + bb[jv * 4 + j];
            *reinterpret_cast<float4*>(op + jv * 4) = u;
        }
    }
}

extern "C" void kernel_launch(void* const* d_in, const int* in_sizes, int n_in,
                              void* d_out, int out_size, void* d_ws, size_t ws_size,
                              hipStream_t stream) {
    const float* x  = (const float*)d_in[0];
    const float* g  = (const float*)d_in[1];
    const float* b  = (const float*)d_in[2];
    const float* wq = (const float*)d_in[3];
    const float* wk = (const float*)d_in[4];
    const float* wv = (const float*)d_in[5];
    const float* wo = (const float*)d_in[6];
    const float* bo = (const float*)d_in[7];
    float* out = (float*)d_out;
    float* ws  = (float*)d_ws;

    int rows = in_sizes[0] / DIM;   // b*p*k = 131072
    int npts = rows / KNB;          // 4096

    hipMemsetAsync(d_ws, 0, 512 * sizeof(float), stream);           // zero BN accumulators
    bn_stats_k<<<256, 256, 0, stream>>>(x, ws, rows / 256);
    bn_finalize_k<<<1, 256, 0, stream>>>(g, b, ws, 1.0f / (float)rows);
    attn_k<<<npts, 256, 0, stream>>>(x, ws, wq, wk, wv, wo, bo, out);
}

// Round 3
// 1171.130 us; speedup vs baseline: 8.7403x; 8.7403x over previous
//
#include <hip/hip_runtime.h>

#define DIM    256
#define HEADS  8
#define DH     64
#define DPG    32
#define KNB    32
#define INNER  512
#define EPS    1e-5f

// ws float offsets
#define WS_SUM  0
#define WS_SSQ  256
#define WS_SC   512
#define WS_SH   768
#define WS_WT_F 1024      // WoutT bf16 [256][512] lives at ws+1024 floats (256 KB)

typedef float f32x4  __attribute__((ext_vector_type(4)));
typedef short bf16x8 __attribute__((ext_vector_type(8)));

__device__ __forceinline__ float lo16(unsigned u){ return __uint_as_float(u << 16); }
__device__ __forceinline__ float hi16(unsigned u){ return __uint_as_float(u & 0xffff0000u); }
__device__ __forceinline__ unsigned short f2bf(float f){
    unsigned u = __float_as_uint(f);
    u += 0x7fffu + ((u >> 16) & 1u);          // RNE
    return (unsigned short)(u >> 16);
}
__device__ __forceinline__ unsigned packbf(float a, float b){
    return (unsigned)f2bf(a) | ((unsigned)f2bf(b) << 16);
}
#define UNPK8(dst, s) { dst[0]=lo16(s.x); dst[1]=hi16(s.x); dst[2]=lo16(s.y); dst[3]=hi16(s.y); \
                        dst[4]=lo16(s.z); dst[5]=hi16(s.z); dst[6]=lo16(s.w); dst[7]=hi16(s.w); }

// ---------------- BN statistics ----------------
__global__ __launch_bounds__(256) void bn_stats_k(const float* __restrict__ x,
                                                  float* __restrict__ ws, int rows_per_block) {
    int c = threadIdx.x;
    long long r0 = (long long)blockIdx.x * rows_per_block;
    float s = 0.f, s2 = 0.f;
    const float* p = x + r0 * DIM + c;
    for (int r = 0; r < rows_per_block; ++r) {
        float v = p[(long long)r * DIM];
        s += v; s2 += v * v;
    }
    atomicAdd(&ws[WS_SUM + c], s);
    atomicAdd(&ws[WS_SSQ + c], s2);
}

__global__ __launch_bounds__(256) void bn_finalize_k(const float* __restrict__ g,
                                                     const float* __restrict__ b,
                                                     float* __restrict__ ws, float inv_n) {
    int c = threadIdx.x;
    float mean = ws[WS_SUM + c] * inv_n;
    float var  = ws[WS_SSQ + c] * inv_n - mean * mean;
    float sc   = g[c] * rsqrtf(var + EPS);
    ws[WS_SC + c] = sc;
    ws[WS_SH + c] = b[c] - mean * sc;
}

// ---------------- Wout transpose to bf16 (ws) ----------------
__global__ __launch_bounds__(256) void wt_k(const float* __restrict__ Wout, float* __restrict__ ws) {
    int k = blockIdx.x;          // 0..511
    int n = threadIdx.x;         // 0..255
    unsigned short* wt = (unsigned short*)(ws + WS_WT_F);
    wt[n * INNER + k] = f2bf(Wout[k * DIM + n]);
}

// ---------------- Phase A: BN(folded) + QKV + attention -> ao bf16 (in d_out) ----------------
// grid (512, 8): blockIdx.y = head; block 128 thr = 2 waves; each wave does 4 points.
__global__ __launch_bounds__(128) void attn_a(const float* __restrict__ x,
                                              const float* __restrict__ ws,
                                              const float* __restrict__ Wq,
                                              const float* __restrict__ Wk,
                                              const float* __restrict__ Wv,
                                              unsigned short* __restrict__ ao) {
    __shared__ __align__(16) unsigned short WTq[DPG][DH];   // [c][o], BN scale folded, bf16
    __shared__ __align__(16) unsigned short WTk[DPG][DH];
    __shared__ __align__(16) unsigned short WTv[DPG][DH];
    __shared__ float qb[3][DH];                              // BN-shift bias per output
    __shared__ __align__(16) unsigned int   xs32[2][KNB][18];   // raw x bf16-pairs, stride 18 uints
    __shared__ __align__(16) unsigned short qs[2][KNB][72];     // q (pre-scaled by 1/8) bf16
    __shared__ __align__(16) unsigned short ks[2][KNB][72];
    __shared__ __align__(16) unsigned short vs[2][KNB][72];
    __shared__ float asl[2][KNB][33];                           // softmax probs fp32

    const int t = threadIdx.x;
    const int h = blockIdx.y;
    const int w = t >> 6;          // wave 0/1
    const int L = t & 63;

    // ---- stage weights (once per block), folding BN scale; compute BN-shift bias
    {
        int o  = t >> 1;             // 0..63
        int ch = (t & 1) * 16;       // 0 or 16
        const float* scp = ws + WS_SC + h * DPG;
        const float* wgq = Wq + (h * DH + o) * DPG + ch;
        const float* wgk = Wk + (h * DH + o) * DPG + ch;
        const float* wgv = Wv + (h * DH + o) * DPG + ch;
        #pragma unroll
        for (int j = 0; j < 16; ++j) {
            float s = scp[ch + j];
            WTq[ch + j][o] = f2bf(wgq[j] * s);
            WTk[ch + j][o] = f2bf(wgk[j] * s);
            WTv[ch + j][o] = f2bf(wgv[j] * s);
        }
        for (int e = t; e < 3 * DH; e += 128) {
            int m = e >> 6, o2 = e & 63;
            const float* wg = (m == 0 ? Wq : (m == 1 ? Wk : Wv)) + (h * DH + o2) * DPG;
            const float* shp = ws + WS_SH + h * DPG;
            float s = 0.f;
            #pragma unroll
            for (int c = 0; c < DPG; ++c) s += shp[c] * wg[c];
            qb[m][o2] = s;
        }
    }
    __syncthreads();

    const int ri = L & 7;
    const int oj = L >> 3;
    const int o0 = oj * 8;

    for (int ip = 0; ip < 4; ++ip) {
        const long long pt = (long long)blockIdx.x * 8 + ip * 2 + w;
        const long long rb = pt * KNB;                    // global row base

        // ---- stage raw x (bf16) for this wave's point
        #pragma unroll
        for (int i = 0; i < 4; ++i) {
            int f = i * 64 + L;
            int r = f >> 3, q4 = f & 7;
            float4 xv = *(const float4*)(x + (rb + r) * DIM + h * DPG + q4 * 4);
            uint2 u;
            u.x = packbf(xv.x, xv.y);
            u.y = packbf(xv.z, xv.w);
            *(uint2*)(&xs32[w][r][q4 * 2]) = u;
        }
        __syncthreads();

        // ---- QKV: lane tile = 4 rows x 8 outs per matrix, K=32
        {
            float aq[4][8], ak[4][8], av[4][8];
            #pragma unroll
            for (int rr = 0; rr < 4; ++rr)
                #pragma unroll
                for (int oo = 0; oo < 8; ++oo) { aq[rr][oo] = 0.f; ak[rr][oo] = 0.f; av[rr][oo] = 0.f; }

            #pragma unroll 4
            for (int c2 = 0; c2 < 16; ++c2) {
                unsigned xp[4];
                #pragma unroll
                for (int rr = 0; rr < 4; ++rr) xp[rr] = xs32[w][ri + 8 * rr][c2];
                uint4 uq0 = *(const uint4*)(&WTq[2 * c2][o0]);
                uint4 uq1 = *(const uint4*)(&WTq[2 * c2 + 1][o0]);
                uint4 uk0 = *(const uint4*)(&WTk[2 * c2][o0]);
                uint4 uk1 = *(const uint4*)(&WTk[2 * c2 + 1][o0]);
                uint4 uv0 = *(const uint4*)(&WTv[2 * c2][o0]);
                uint4 uv1 = *(const uint4*)(&WTv[2 * c2 + 1][o0]);
                float wq0[8], wq1[8], wk0[8], wk1[8], wv0[8], wv1[8];
                UNPK8(wq0, uq0); UNPK8(wq1, uq1);
                UNPK8(wk0, uk0); UNPK8(wk1, uk1);
                UNPK8(wv0, uv0); UNPK8(wv1, uv1);
                #pragma unroll
                for (int rr = 0; rr < 4; ++rr) {
                    float xl = lo16(xp[rr]), xh = hi16(xp[rr]);
                    #pragma unroll
                    for (int oo = 0; oo < 8; ++oo) {
                        aq[rr][oo] += xl * wq0[oo] + xh * wq1[oo];
                        ak[rr][oo] += xl * wk0[oo] + xh * wk1[oo];
                        av[rr][oo] += xl * wv0[oo] + xh * wv1[oo];
                    }
                }
            }
            // add BN-shift bias, pack, store (q pre-scaled by dim_head^-0.5)
            float qbq[8], qbk[8], qbv[8];
            #pragma unroll
            for (int oo = 0; oo < 8; ++oo) { qbq[oo] = qb[0][o0 + oo]; qbk[oo] = qb[1][o0 + oo]; qbv[oo] = qb[2][o0 + oo]; }
            #pragma unroll
            for (int rr = 0; rr < 4; ++rr) {
                int row = ri + 8 * rr;
                uint4 u;
                u.x = packbf((aq[rr][0] + qbq[0]) * 0.125f, (aq[rr][1] + qbq[1]) * 0.125f);
                u.y = packbf((aq[rr][2] + qbq[2]) * 0.125f, (aq[rr][3] + qbq[3]) * 0.125f);
                u.z = packbf((aq[rr][4] + qbq[4]) * 0.125f, (aq[rr][5] + qbq[5]) * 0.125f);
                u.w = packbf((aq[rr][6] + qbq[6]) * 0.125f, (aq[rr][7] + qbq[7]) * 0.125f);
                *(uint4*)(&qs[w][row][o0]) = u;
                u.x = packbf(ak[rr][0] + qbk[0], ak[rr][1] + qbk[1]);
                u.y = packbf(ak[rr][2] + qbk[2], ak[rr][3] + qbk[3]);
                u.z = packbf(ak[rr][4] + qbk[4], ak[rr][5] + qbk[5]);
                u.w = packbf(ak[rr][6] + qbk[6], ak[rr][7] + qbk[7]);
                *(uint4*)(&ks[w][row][o0]) = u;
                u.x = packbf(av[rr][0] + qbv[0], av[rr][1] + qbv[1]);
                u.y = packbf(av[rr][2] + qbv[2], av[rr][3] + qbv[3]);
                u.z = packbf(av[rr][4] + qbv[4], av[rr][5] + qbv[5]);
                u.w = packbf(av[rr][6] + qbv[6], av[rr][7] + qbv[7]);
                *(uint4*)(&vs[w][row][o0]) = u;
            }
        }
        __syncthreads();

        // ---- dots + softmax: lane tile 4 rows (ri+8rr) x 4 cols (ji*4+jj), K=64
        {
            const int ji = L >> 3;
            float dt[4][4];
            #pragma unroll
            for (int rr = 0; rr < 4; ++rr)
                #pragma unroll
                for (int jj = 0; jj < 4; ++jj) dt[rr][jj] = 0.f;

            #pragma unroll
            for (int dj = 0; dj < 8; ++dj) {
                float qf[4][8], kf[4][8];
                #pragma unroll
                for (int rr = 0; rr < 4; ++rr) {
                    uint4 u = *(const uint4*)(&qs[w][ri + 8 * rr][dj * 8]);
                    UNPK8(qf[rr], u);
                }
                #pragma unroll
                for (int jj = 0; jj < 4; ++jj) {
                    uint4 u = *(const uint4*)(&ks[w][ji * 4 + jj][dj * 8]);
                    UNPK8(kf[jj], u);
                }
                #pragma unroll
                for (int rr = 0; rr < 4; ++rr)
                    #pragma unroll
                    for (int jj = 0; jj < 4; ++jj) {
                        float s = dt[rr][jj];
                        #pragma unroll
                        for (int e = 0; e < 8; ++e) s += qf[rr][e] * kf[jj][e];
                        dt[rr][jj] = s;
                    }
            }
            // softmax over 32 cols: 4 local + xor across ji lanes (masks 8,16,32)
            float mrow[4], srow[4];
            #pragma unroll
            for (int rr = 0; rr < 4; ++rr)
                mrow[rr] = fmaxf(fmaxf(dt[rr][0], dt[rr][1]), fmaxf(dt[rr][2], dt[rr][3]));
            #pragma unroll
            for (int rr = 0; rr < 4; ++rr) {
                mrow[rr] = fmaxf(mrow[rr], __shfl_xor(mrow[rr], 8, 64));
                mrow[rr] = fmaxf(mrow[rr], __shfl_xor(mrow[rr], 16, 64));
                mrow[rr] = fmaxf(mrow[rr], __shfl_xor(mrow[rr], 32, 64));
            }
            #pragma unroll
            for (int rr = 0; rr < 4; ++rr) {
                float s = 0.f;
                #pragma unroll
                for (int jj = 0; jj < 4; ++jj) { dt[rr][jj] = __expf(dt[rr][jj] - mrow[rr]); s += dt[rr][jj]; }
                srow[rr] = s;
            }
            #pragma unroll
            for (int rr = 0; rr < 4; ++rr) {
                srow[rr] += __shfl_xor(srow[rr], 8, 64);
                srow[rr] += __shfl_xor(srow[rr], 16, 64);
                srow[rr] += __shfl_xor(srow[rr], 32, 64);
            }
            #pragma unroll
            for (int rr = 0; rr < 4; ++rr) {
                float inv = 1.f / srow[rr];
                #pragma unroll
                for (int jj = 0; jj < 4; ++jj)
                    asl[w][ri + 8 * rr][ji * 4 + jj] = dt[rr][jj] * inv;
            }
        }
        __syncthreads();

        // ---- AV: lane tile 4 rows x 8 out-cols, K=32; write ao bf16 to global
        {
            float av2[4][8];
            #pragma unroll
            for (int rr = 0; rr < 4; ++rr)
                #pragma unroll
                for (int oo = 0; oo < 8; ++oo) av2[rr][oo] = 0.f;

            #pragma unroll 8
            for (int j = 0; j < KNB; ++j) {
                float aarr[4];
                #pragma unroll
                for (int rr = 0; rr < 4; ++rr) aarr[rr] = asl[w][ri + 8 * rr][j];
                uint4 vv = *(const uint4*)(&vs[w][j][o0]);
                float vf[8];
                UNPK8(vf, vv);
                #pragma unroll
                for (int rr = 0; rr < 4; ++rr)
                    #pragma unroll
                    for (int oo = 0; oo < 8; ++oo) av2[rr][oo] += aarr[rr] * vf[oo];
            }
            #pragma unroll
            for (int rr = 0; rr < 4; ++rr) {
                uint4 u;
                u.x = packbf(av2[rr][0], av2[rr][1]);
                u.y = packbf(av2[rr][2], av2[rr][3]);
                u.z = packbf(av2[rr][4], av2[rr][5]);
                u.w = packbf(av2[rr][6], av2[rr][7]);
                *(uint4*)(ao + (rb + ri + 8 * rr) * INNER + h * DH + o0) = u;
            }
        }
        __syncthreads();
    }
}

// ---------------- Phase B: MFMA GEMM  out = ao[131072x512]bf16 @ WoutT^T + bout (in-place on d_out)
__global__ __launch_bounds__(256) void gemm_b(const unsigned short* __restrict__ aoC,
                                              const float* __restrict__ ws,
                                              const float* __restrict__ bout,
                                              float* __restrict__ outF) {
    __shared__ __align__(16) uint4 As4[64 * 64];   // 64 rows x 512 bf16, XOR-swizzled chunks
    const unsigned short* WT = (const unsigned short*)(ws + WS_WT_F);
    const int t = threadIdx.x;
    const long long row0 = (long long)blockIdx.x * 64;

    // stage A-tile (read-before-overwrite makes in-place safe)
    #pragma unroll
    for (int i = 0; i < 16; ++i) {
        int e = t + 256 * i;
        int r = e >> 6, off = e & 63;
        uint4 u = *(const uint4*)(aoC + (row0 + r) * INNER + off * 8);
        As4[r * 64 + (off ^ (r & 7))] = u;
    }
    __syncthreads();

    const int w = t >> 6, L = t & 63;
    const int m  = w * 16 + (L & 15);
    const int kg = L >> 4;                 // k-octet group 0..3

    f32x4 acc[16];
    #pragma unroll
    for (int nt = 0; nt < 16; ++nt) acc[nt] = (f32x4){0.f, 0.f, 0.f, 0.f};

    #pragma unroll 4
    for (int kk = 0; kk < 16; ++kk) {
        uint4 a_u = As4[m * 64 + ((kk * 4 + kg) ^ (m & 7))];
        bf16x8 af = *(bf16x8*)&a_u;
        #pragma unroll
        for (int nt = 0; nt < 16; ++nt) {
            int n = nt * 16 + (L & 15);
            bf16x8 bv = *(const bf16x8*)(WT + (size_t)n * INNER + kk * 32 + kg * 8);
            acc[nt] = __builtin_amdgcn_mfma_f32_16x16x32_bf16(af, bv, acc[nt], 0, 0, 0);
        }
    }

    // epilogue: C layout col=lane&15, row=(lane>>4)*4+reg
    const int colb  = L & 15;
    const int rquad = (L >> 4) * 4;
    #pragma unroll
    for (int nt = 0; nt < 16; ++nt) {
        int col = nt * 16 + colb;
        float bval = bout[col];
        #pragma unroll
        for (int reg = 0; reg < 4; ++reg)
            outF[(row0 + w * 16 + rquad + reg) * DIM + col] = acc[nt][reg] + bval;
    }
}

extern "C" void kernel_launch(void* const* d_in, const int* in_sizes, int n_in,
                              void* d_out, int out_size, void* d_ws, size_t ws_size,
                              hipStream_t stream) {
    const float* x  = (const float*)d_in[0];
    const float* g  = (const float*)d_in[1];
    const float* b  = (const float*)d_in[2];
    const float* wq = (const float*)d_in[3];
    const float* wk = (const float*)d_in[4];
    const float* wv = (const float*)d_in[5];
    const float* wo = (const float*)d_in[6];
    const float* bo = (const float*)d_in[7];
    float* ws = (float*)d_ws;

    int rows = in_sizes[0] / DIM;       // 131072
    int npts = rows / KNB;              // 4096

    hipMemsetAsync(d_ws, 0, 2048, stream);
    bn_stats_k<<<256, 256, 0, stream>>>(x, ws, rows / 256);
    bn_finalize_k<<<1, 256, 0, stream>>>(g, b, ws, 1.0f / (float)rows);
    wt_k<<<INNER, 256, 0, stream>>>(wo, ws);
    attn_a<<<dim3(npts / 8, HEADS), 128, 0, stream>>>(x, ws, wq, wk, wv, (unsigned short*)d_out);
    gemm_b<<<rows / 64, 256, 0, stream>>>((const unsigned short*)d_out, ws, bo, (float*)d_out);
}